// Round 10
// baseline (7347.219 us; speedup 1.0000x reference)
//
#include <hip/hip_runtime.h>

// Problem constants (match reference)
#define TT 4096   // sequence length
#define SD 64     // shared features
#define PD 8      // per-device features
#define DD 32     // devices
#define HH 128    // hidden
#define NG 512    // 4*H gate rows
#define XD 72     // S+P
#define XPAIRS 36 // packed f16x2 pairs of x
#define GXTB 16   // t-tile of the gx precompute kernel

typedef _Float16 h2 __attribute__((ext_vector_type(2)));
typedef _Float16 f16x8 __attribute__((ext_vector_type(8)));
typedef float f32x4 __attribute__((ext_vector_type(4)));
typedef unsigned u32x4 __attribute__((ext_vector_type(4)));
typedef unsigned short u16x4 __attribute__((ext_vector_type(4)));
typedef unsigned uv16 __attribute__((ext_vector_type(16)));
typedef unsigned uv4 __attribute__((ext_vector_type(4)));

#if defined(__has_builtin)
#  if __has_builtin(__builtin_amdgcn_fdot2)
#    define USE_DOT2 1
#  endif
#endif

__device__ __forceinline__ unsigned pack_h2(float a, float b) {
  unsigned short ua = __builtin_bit_cast(unsigned short, (_Float16)a);
  unsigned short ub = __builtin_bit_cast(unsigned short, (_Float16)b);
  return ((unsigned)ub << 16) | ua;
}
__device__ __forceinline__ unsigned short f16bits(float a) {
  return __builtin_bit_cast(unsigned short, (_Float16)a);
}
__device__ __forceinline__ float f16val(unsigned short u) {
  return (float)__builtin_bit_cast(_Float16, u);
}
__device__ __forceinline__ float dot2(unsigned w, unsigned h, float acc) {
#ifdef USE_DOT2
  return __builtin_amdgcn_fdot2(__builtin_bit_cast(h2, w),
                                __builtin_bit_cast(h2, h), acc, false);
#else
  h2 wv = __builtin_bit_cast(h2, w), hv = __builtin_bit_cast(h2, h);
  return __builtin_fmaf((float)wv[1], (float)hv[1],
                        __builtin_fmaf((float)wv[0], (float)hv[0], acc));
#endif
}
__device__ __forceinline__ float fast_sigmoid(float x) { return 1.0f / (1.0f + __expf(-x)); }
__device__ __forceinline__ float fast_tanh(float x) { return 2.0f / (1.0f + __expf(-2.0f * x)) - 1.0f; }

// load 8 consecutive fp32 -> f16x8 SSA vector (A-fragment slots, k ascending)
__device__ __forceinline__ f16x8 ldfrag8(const float* __restrict__ p) {
  f16x8 v;
#pragma unroll
  for (int j = 0; j < 8; ++j) v[j] = (_Float16)p[j];
  return v;
}

// Compiler intrinsic MFMA: visible semantics -> compiler manages ALL hazards,
// wait-states, and AGPR/VGPR assignment (the R7-R9 raw-asm traps are gone).
__device__ __forceinline__ f32x4 mf(f16x8 a, u32x4 braw, f32x4 c) {
  return __builtin_amdgcn_mfma_f32_16x16x32_f16(a, __builtin_bit_cast(f16x8, braw), c, 0, 0, 0);
}

#define WA_LIST(X) X(0) X(1) X(2) X(3) X(4) X(5) X(6) X(7) \
                   X(8) X(9) X(10) X(11) X(12) X(13) X(14) X(15)
#define WC_LIST(X) X(0) X(1) X(2) X(3) X(4) X(5) X(6) X(7) \
                   X(8) X(9) X(10) X(11) X(12) X(13) X(14) X(15) \
                   X(16) X(17) X(18) X(19) X(20) X(21) X(22) X(23) \
                   X(24) X(25) X(26) X(27) X(28) X(29) X(30) X(31)

// ---------------------------------------------------------------------------
// gx precompute: gx2[d][t][j][q] = f16( b0[d][g] + Wih0[d][g]·x[d][t] ), g=q*128+j
// ---------------------------------------------------------------------------
__global__ __launch_bounds__(512)
void gx_kernel(const float* __restrict__ shared_in, const float* __restrict__ perdev,
               const float* __restrict__ Wih0, const float* __restrict__ b0,
               unsigned short* __restrict__ gx2)
{
  const int d = blockIdx.y;
  const int t0 = blockIdx.x * GXTB;
  const int g = threadIdx.x;
  __shared__ unsigned xs[GXTB * XPAIRS];

  const float* p = Wih0 + (size_t)(d * NG + g) * XD;
  uv16 w0, w1; uv4 w2;
#pragma unroll
  for (int j = 0; j < 16; ++j) w0[j] = pack_h2(p[2*j], p[2*j+1]);
#pragma unroll
  for (int j = 0; j < 16; ++j) w1[j] = pack_h2(p[32+2*j], p[33+2*j]);
#pragma unroll
  for (int j = 0; j < 4; ++j) w2[j] = pack_h2(p[64+2*j], p[65+2*j]);
  const float b0g = b0[d * NG + g];

  for (int i = g; i < GXTB * XPAIRS; i += 512) {
    int r = i / XPAIRS, j = i - r * XPAIRS, t = t0 + r;
    float a, b;
    if (j < SD/2) { a = shared_in[t*SD + 2*j]; b = shared_in[t*SD + 2*j + 1]; }
    else { int k = 2*(j - SD/2); a = perdev[((size_t)d*TT + t)*PD + k]; b = perdev[((size_t)d*TT + t)*PD + k + 1]; }
    xs[i] = pack_h2(a, b);
  }
  __syncthreads();

#define WJ(j) ((j) < 16 ? w0[(j)] : ((j) < 32 ? w1[(j)-16] : w2[(j)-32]))
  for (int tt = 0; tt < GXTB; ++tt) {
    const unsigned* xr = &xs[tt * XPAIRS];
    float a0 = b0g, a1 = 0.f, a2 = 0.f, a3 = 0.f;
#pragma unroll
    for (int j = 0; j < XPAIRS; j += 4) {
      a0 = dot2(WJ(j+0), xr[j+0], a0); a1 = dot2(WJ(j+1), xr[j+1], a1);
      a2 = dot2(WJ(j+2), xr[j+2], a2); a3 = dot2(WJ(j+3), xr[j+3], a3);
    }
    gx2[(((size_t)d*TT + t0 + tt) * 128 + (g & 127)) * 4 + (g >> 7)] = f16bits((a0+a1)+(a2+a3));
  }
#undef WJ
}

// ---------------------------------------------------------------------------
// Main recurrence: MFMA gates via compiler intrinsics.
// 512 threads = 8 waves; wave wv owns gate rows [64wv, 64wv+64) as 4 tiles.
// A-frag 16x16x32: A[m=lane&15][k=8*quad+j] (any HW k-permutation cancels:
// A and B are filled with the same slot convention). B: every lane loads the
// same h chunk -> all 16 D columns equal A·h; only column 0 (mrow==0) is read.
// C/D: col=lane&15, row=quad*4+reg (m89-verified, dtype-independent).
// waves_per_eu(2,2): 512-unified-reg/wave ceiling, fits 192 weight regs + work.
// ---------------------------------------------------------------------------
__global__ __attribute__((amdgpu_flat_work_group_size(512, 512), amdgpu_waves_per_eu(2, 2)))
void lstm_mfma(const float* __restrict__ Whh0,        // [D, 4H, H]
               const float* __restrict__ Wih1,        // [D, 4H, H]
               const float* __restrict__ Whh1,        // [D, 4H, H]
               const float* __restrict__ b1,          // [D, 4H]
               const float* __restrict__ Wout,        // [D, H]
               const float* __restrict__ bout,        // [D]
               const unsigned short* __restrict__ gxp,// [D, T, 128, 4] f16
               float* __restrict__ out)               // [T, D]
{
  const int d = blockIdx.x;
  const int g = threadIdx.x;
  const int lane = g & 63;
  const int wv = g >> 6;
  const int mrow = lane & 15;
  const int quad = lane >> 4;

  __shared__ __align__(16) unsigned hs_u[HH];   // f16: uints [0:64)=h0, [64:128)=h1
  __shared__ __align__(16) float p0_s[NG];      // layer-0 raw MFMA preacts
  __shared__ __align__(16) float p1_s[NG];      // layer-1 raw MFMA preacts
  __shared__ float part_s[2];

  // ---- weight fragments (individual SSA vectors; compiler places in AGPRs) ----
  const float* w0p = Whh0 + (size_t)d * NG * HH;  // layer0, K=128: wa[T*4+C]
  const float* w1p = Wih1 + (size_t)d * NG * HH;  // layer1 K-chunks 0..3
  const float* w2p = Whh1 + (size_t)d * NG * HH;  // layer1 K-chunks 4..7
#define DWA(n) f16x8 wa##n = ldfrag8(w0p + (size_t)(64*wv + 16*((n)/4) + mrow)*HH + 32*((n)%4) + 8*quad);
  WA_LIST(DWA)
#undef DWA
#define DWC(n) f16x8 wc##n = ldfrag8(((n)%8 < 4 ? w1p + (size_t)(64*wv + 16*((n)/8) + mrow)*HH + 32*((n)%8) + 8*quad \
                                                : w2p + (size_t)(64*wv + 16*((n)/8) + mrow)*HH + 32*((n)%8-4) + 8*quad));
  WC_LIST(DWC)
#undef DWC

  // ---- per-thread scalars ----
  float c0v = 0.f, c1v = 0.f;
  float b1i = 0.f, b1f = 0.f, b1g_ = 0.f, b1o = 0.f, woutj = 0.f;
  if (g < HH) {
    b1i = b1[d*NG + g]; b1f = b1[d*NG + g + 128];
    b1g_ = b1[d*NG + g + 256]; b1o = b1[d*NG + g + 384];
    woutj = Wout[d*HH + g];
  }
  const float boutd = bout[d];

  if (g < HH) hs_u[g] = 0u;  // zero h0,h1
  u16x4 gxc4 = {0,0,0,0}, gxn4 = {0,0,0,0};
  if (g < HH) gxc4 = *(const u16x4*)(gxp + (((size_t)d*TT + 0)*128 + g)*4);

  const f32x4 zc = {0.f, 0.f, 0.f, 0.f};
  __syncthreads();

  for (int t = 0; t < TT; ++t) {
    // ---- phase A: p0 = Whh0 · h0 (MFMA, K=128) ----
    {
      const u32x4* hb = (const u32x4*)hs_u;
      u32x4 bm0 = hb[quad], bm1 = hb[4+quad], bm2 = hb[8+quad], bm3 = hb[12+quad];
      f32x4 ac0 = mf(wa0,  bm0, zc), ac1 = mf(wa4,  bm0, zc),
            ac2 = mf(wa8,  bm0, zc), ac3 = mf(wa12, bm0, zc);
      ac0 = mf(wa1,  bm1, ac0); ac1 = mf(wa5,  bm1, ac1); ac2 = mf(wa9,  bm1, ac2); ac3 = mf(wa13, bm1, ac3);
      ac0 = mf(wa2,  bm2, ac0); ac1 = mf(wa6,  bm2, ac1); ac2 = mf(wa10, bm2, ac2); ac3 = mf(wa14, bm2, ac3);
      ac0 = mf(wa3,  bm3, ac0); ac1 = mf(wa7,  bm3, ac1); ac2 = mf(wa11, bm3, ac2); ac3 = mf(wa15, bm3, ac3);
      if (mrow == 0) {
        int base = 64*wv + 4*quad;
        *(f32x4*)&p0_s[base     ] = ac0;
        *(f32x4*)&p0_s[base + 16] = ac1;
        *(f32x4*)&p0_s[base + 32] = ac2;
        *(f32x4*)&p0_s[base + 48] = ac3;
      }
    }
    __syncthreads();  // barrier 1

    // deferred output store for t-1 (wave 7 is idle in phase B)
    if (g == 511 && t > 0) out[(size_t)(t-1)*DD + d] = part_s[0] + part_s[1] + boutd;

    // ---- phase B: layer-0 activations + cell (threads 0..127) ----
    if (g < HH) {
      float pi = p0_s[g]       + f16val(gxc4[0]);
      float pf = p0_s[g + 128] + f16val(gxc4[1]);
      float pg = p0_s[g + 256] + f16val(gxc4[2]);
      float po = p0_s[g + 384] + f16val(gxc4[3]);
      c0v = fast_sigmoid(pf) * c0v + fast_sigmoid(pi) * fast_tanh(pg);
      float h0n = fast_sigmoid(po) * fast_tanh(c0v);
      ((unsigned short*)hs_u)[g] = f16bits(h0n);
      if (t + 1 < TT) gxn4 = *(const u16x4*)(gxp + (((size_t)d*TT + t + 1)*128 + g)*4);
    }
    __syncthreads();  // barrier 2

    // ---- phase C: p1 = [Wih1|Whh1] · [h0;h1] (MFMA, K=256) ----
    {
      const u32x4* hb = (const u32x4*)hs_u;
      u32x4 bm0 = hb[quad], bm1 = hb[4+quad], bm2 = hb[8+quad], bm3 = hb[12+quad];
      f32x4 ac0 = mf(wc0, bm0, zc), ac1 = mf(wc8,  bm0, zc),
            ac2 = mf(wc16, bm0, zc), ac3 = mf(wc24, bm0, zc);
      ac0 = mf(wc1, bm1, ac0); ac1 = mf(wc9,  bm1, ac1); ac2 = mf(wc17, bm1, ac2); ac3 = mf(wc25, bm1, ac3);
      ac0 = mf(wc2, bm2, ac0); ac1 = mf(wc10, bm2, ac1); ac2 = mf(wc18, bm2, ac2); ac3 = mf(wc26, bm2, ac3);
      ac0 = mf(wc3, bm3, ac0); ac1 = mf(wc11, bm3, ac1); ac2 = mf(wc19, bm3, ac2); ac3 = mf(wc27, bm3, ac3);
      bm0 = hb[16+quad]; bm1 = hb[20+quad]; bm2 = hb[24+quad]; bm3 = hb[28+quad];
      ac0 = mf(wc4, bm0, ac0); ac1 = mf(wc12, bm0, ac1); ac2 = mf(wc20, bm0, ac2); ac3 = mf(wc28, bm0, ac3);
      ac0 = mf(wc5, bm1, ac0); ac1 = mf(wc13, bm1, ac1); ac2 = mf(wc21, bm1, ac2); ac3 = mf(wc29, bm1, ac3);
      ac0 = mf(wc6, bm2, ac0); ac1 = mf(wc14, bm2, ac1); ac2 = mf(wc22, bm2, ac2); ac3 = mf(wc30, bm2, ac3);
      ac0 = mf(wc7, bm3, ac0); ac1 = mf(wc15, bm3, ac1); ac2 = mf(wc23, bm3, ac2); ac3 = mf(wc31, bm3, ac3);
      if (mrow == 0) {
        int base = 64*wv + 4*quad;
        *(f32x4*)&p1_s[base     ] = ac0;
        *(f32x4*)&p1_s[base + 16] = ac1;
        *(f32x4*)&p1_s[base + 32] = ac2;
        *(f32x4*)&p1_s[base + 48] = ac3;
      }
    }
    __syncthreads();  // barrier 3

    // ---- phase D: layer-1 activations + cell + output partial (threads 0..127) ----
    if (g < HH) {
      float pi = p1_s[g]       + b1i;
      float pf = p1_s[g + 128] + b1f;
      float pg = p1_s[g + 256] + b1g_;
      float po = p1_s[g + 384] + b1o;
      c1v = fast_sigmoid(pf) * c1v + fast_sigmoid(pi) * fast_tanh(pg);
      float h1n = fast_sigmoid(po) * fast_tanh(c1v);
      ((unsigned short*)hs_u)[HH + g] = f16bits(h1n);
      float p = woutj * h1n;
#pragma unroll
      for (int off = 32; off > 0; off >>= 1) p += __shfl_down(p, off, 64);
      if (lane == 0) part_s[wv] = p;
    }
    gxc4 = gxn4;
    // no barrier: phase A(t+1) reads h0 + writes p0_s only — disjoint from
    // phase D's writes (h1 region, part_s). part_s read after barrier 1(t+1);
    // h1 read in phase C(t+1), two barriers downstream.
  }

  __syncthreads();
  if (g == 511) out[(size_t)(TT-1)*DD + d] = part_s[0] + part_s[1] + boutd;
}

// ---------------------------------------------------------------------------
// Fallback (ws too small): correct, slow, weights streamed from global.
// ---------------------------------------------------------------------------
__global__ __launch_bounds__(512)
void lstm_slow(const float* __restrict__ shared_in, const float* __restrict__ perdev,
               const float* __restrict__ Wih0, const float* __restrict__ Whh0,
               const float* __restrict__ b0, const float* __restrict__ Wih1,
               const float* __restrict__ Whh1, const float* __restrict__ b1,
               const float* __restrict__ Wout, const float* __restrict__ bout,
               float* __restrict__ out)
{
  const int d = blockIdx.x, g = threadIdx.x;
  __shared__ float xf[XD], h0f[HH], h1f[HH], act0[NG], act1[NG], part[2];
  float c0 = 0.f, c1 = 0.f;
  const bool tg = ((g >> 7) == 2);
  if (g < HH) { h0f[g] = 0.f; h1f[g] = 0.f; }
  __syncthreads();
  for (int t = 0; t < TT; ++t) {
    if (g < SD) xf[g] = shared_in[t*SD + g];
    else if (g < XD) xf[g] = perdev[((size_t)d*TT + t)*PD + (g - SD)];
    __syncthreads();
    {
      const float* wr = Wih0 + (size_t)(d*NG + g)*XD;
      float a = b0[d*NG + g];
      for (int k = 0; k < XD; ++k) a += wr[k]*xf[k];
      const float* hr = Whh0 + (size_t)(d*NG + g)*HH;
      for (int k = 0; k < HH; ++k) a += hr[k]*h0f[k];
      act0[g] = tg ? fast_tanh(a) : fast_sigmoid(a);
    }
    __syncthreads();
    if (g < HH) {
      c0 = act0[g+128]*c0 + act0[g]*act0[g+256];
      h0f[g] = act0[g+384]*fast_tanh(c0);
    }
    __syncthreads();
    {
      const float* ir = Wih1 + (size_t)(d*NG + g)*HH;
      const float* hr = Whh1 + (size_t)(d*NG + g)*HH;
      float a = b1[d*NG + g];
      for (int k = 0; k < HH; ++k) a += ir[k]*h0f[k] + hr[k]*h1f[k];
      act1[g] = tg ? fast_tanh(a) : fast_sigmoid(a);
    }
    __syncthreads();
    if (g < HH) {
      c1 = act1[g+128]*c1 + act1[g]*act1[g+256];
      float h1n = act1[g+384]*fast_tanh(c1);
      h1f[g] = h1n;
      float p = Wout[d*HH + g]*h1n;
#pragma unroll
      for (int off = 32; off > 0; off >>= 1) p += __shfl_down(p, off, 64);
      if ((g & 63) == 0) part[g >> 6] = p;
    }
    __syncthreads();
    if (g == 0) out[(size_t)t*DD + d] = part[0] + part[1] + bout[d];
    __syncthreads();
  }
}

extern "C" void kernel_launch(void* const* d_in, const int* in_sizes, int n_in,
                              void* d_out, int out_size, void* d_ws, size_t ws_size,
                              hipStream_t stream) {
  const float* shared_in = (const float*)d_in[0];
  const float* perdev    = (const float*)d_in[1];
  const float* Wih0      = (const float*)d_in[2];
  const float* Whh0      = (const float*)d_in[3];
  const float* b0        = (const float*)d_in[4];
  const float* Wih1      = (const float*)d_in[5];
  const float* Whh1      = (const float*)d_in[6];
  const float* b1        = (const float*)d_in[7];
  const float* Wout      = (const float*)d_in[8];
  const float* bout      = (const float*)d_in[9];
  float* out = (float*)d_out;

  const size_t gx_bytes = (size_t)DD * TT * NG * sizeof(unsigned short);  // 128 MB
  if (ws_size >= gx_bytes) {
    unsigned short* gxp = (unsigned short*)d_ws;
    gx_kernel<<<dim3(TT / GXTB, DD), dim3(512), 0, stream>>>(shared_in, perdev, Wih0, b0, gxp);
    lstm_mfma<<<dim3(DD), dim3(512), 0, stream>>>(Whh0, Wih1, Whh1, b1, Wout, bout, gxp, out);
  } else {
    lstm_slow<<<dim3(DD), dim3(512), 0, stream>>>(shared_in, perdev, Wih0, Whh0, b0,
                                                  Wih1, Whh1, b1, Wout, bout, out);
  }
}